// Round 1
// baseline (3844.198 us; speedup 1.0000x reference)
//
#include <hip/hip_runtime.h>
#include <hip/hip_bf16.h>
#include <cstdint>
#include <cstddef>

#define TOPK 64

// Monotone map: descending float order == descending unsigned key order.
__device__ __forceinline__ unsigned fkey(float f) {
    unsigned u = __float_as_uint(f);
    return (u & 0x80000000u) ? ~u : (u | 0x80000000u);
}

// ---------------------------------------------------------------------------
// Kernel 1: inv_norm[h] = g_enc[h] / ||v_enc[h,:]||   (one block per row)
// ---------------------------------------------------------------------------
__global__ __launch_bounds__(256)
void enc_norm_kernel(const float* __restrict__ v_enc,
                     const float* __restrict__ g_enc,
                     float* __restrict__ inv_norm, int H, int D) {
    int h = blockIdx.x;
    if (h >= H) return;
    const float* row = v_enc + (size_t)h * D;
    float ss = 0.f;
    for (int i = threadIdx.x; i < D; i += blockDim.x) {
        float v = row[i];
        ss += v * v;
    }
    for (int off = 32; off > 0; off >>= 1) ss += __shfl_down(ss, off, 64);
    __shared__ float s_part[4];
    int lane = threadIdx.x & 63, wv = threadIdx.x >> 6;
    if (lane == 0) s_part[wv] = ss;
    __syncthreads();
    if (threadIdx.x == 0) {
        float t = s_part[0] + s_part[1] + s_part[2] + s_part[3];
        inv_norm[h] = g_enc[h] / sqrtf(t);
    }
}

// ---------------------------------------------------------------------------
// Kernel 2: z[n,h] = dot(x[n,:], v_enc[h,:]) * inv_norm[h] + b_enc[h]
// fp32 VALU GEMM, 128x128 tile, BK=16, 256 threads, 8x8 acc/thread.
// ---------------------------------------------------------------------------
#define BM 128
#define BN 128
#define BK 16

__global__ __launch_bounds__(256)
void enc_gemm_kernel(const float* __restrict__ x,
                     const float* __restrict__ v_enc,
                     const float* __restrict__ inv_norm,
                     const float* __restrict__ b_enc,
                     float* __restrict__ z,
                     int N, int D, int H) {
    __shared__ float As[BK][BM];   // transposed: As[k][m]
    __shared__ float Bs[BK][BN];   // transposed: Bs[k][h]
    const int tid = threadIdx.x;
    const int m0 = blockIdx.y * BM;
    const int h0 = blockIdx.x * BN;
    const int tx = tid & 15;   // col group
    const int ty = tid >> 4;   // row group

    float acc[8][8];
#pragma unroll
    for (int i = 0; i < 8; i++)
#pragma unroll
        for (int j = 0; j < 8; j++) acc[i][j] = 0.f;

    for (int k0 = 0; k0 < D; k0 += BK) {
        // Stage A tile: 128 rows x 16 k = 512 float4; 2 per thread.
#pragma unroll
        for (int s = 0; s < 2; ++s) {
            int idx = tid + s * 256;
            int row = idx >> 2, kq = (idx & 3) * 4;
            const float4 av = *(const float4*)(x + (size_t)(m0 + row) * D + k0 + kq);
            As[kq + 0][row] = av.x;
            As[kq + 1][row] = av.y;
            As[kq + 2][row] = av.z;
            As[kq + 3][row] = av.w;
        }
        // Stage B tile (guard h).
#pragma unroll
        for (int s = 0; s < 2; ++s) {
            int idx = tid + s * 256;
            int row = idx >> 2, kq = (idx & 3) * 4;
            int h = h0 + row;
            float4 bv = make_float4(0.f, 0.f, 0.f, 0.f);
            if (h < H) bv = *(const float4*)(v_enc + (size_t)h * D + k0 + kq);
            Bs[kq + 0][row] = bv.x;
            Bs[kq + 1][row] = bv.y;
            Bs[kq + 2][row] = bv.z;
            Bs[kq + 3][row] = bv.w;
        }
        __syncthreads();
#pragma unroll
        for (int k = 0; k < BK; k++) {
            float a[8], b[8];
            *(float4*)&a[0] = *(const float4*)&As[k][ty * 4];
            *(float4*)&a[4] = *(const float4*)&As[k][64 + ty * 4];
            *(float4*)&b[0] = *(const float4*)&Bs[k][tx * 4];
            *(float4*)&b[4] = *(const float4*)&Bs[k][64 + tx * 4];
#pragma unroll
            for (int i = 0; i < 8; i++)
#pragma unroll
                for (int j = 0; j < 8; j++)
                    acc[i][j] = fmaf(a[i], b[j], acc[i][j]);
        }
        __syncthreads();
    }

    // Epilogue: scale by inv_norm, add bias, store.
#pragma unroll
    for (int i = 0; i < 8; i++) {
        int m = m0 + ((i < 4) ? (ty * 4 + i) : (64 + ty * 4 + i - 4));
        size_t base = (size_t)m * H;
        int h_lo = h0 + tx * 4;
        int h_hi = h0 + 64 + tx * 4;
        if (h_lo + 4 <= H) {
            float4 o;
            o.x = fmaf(acc[i][0], inv_norm[h_lo + 0], b_enc[h_lo + 0]);
            o.y = fmaf(acc[i][1], inv_norm[h_lo + 1], b_enc[h_lo + 1]);
            o.z = fmaf(acc[i][2], inv_norm[h_lo + 2], b_enc[h_lo + 2]);
            o.w = fmaf(acc[i][3], inv_norm[h_lo + 3], b_enc[h_lo + 3]);
            *(float4*)(z + base + h_lo) = o;
        } else {
#pragma unroll
            for (int j = 0; j < 4; j++) {
                int h = h_lo + j;
                if (h < H) z[base + h] = fmaf(acc[i][j], inv_norm[h], b_enc[h]);
            }
        }
        if (h_hi + 4 <= H) {
            float4 o;
            o.x = fmaf(acc[i][4], inv_norm[h_hi + 0], b_enc[h_hi + 0]);
            o.y = fmaf(acc[i][5], inv_norm[h_hi + 1], b_enc[h_hi + 1]);
            o.z = fmaf(acc[i][6], inv_norm[h_hi + 2], b_enc[h_hi + 2]);
            o.w = fmaf(acc[i][7], inv_norm[h_hi + 3], b_enc[h_hi + 3]);
            *(float4*)(z + base + h_hi) = o;
        } else {
#pragma unroll
            for (int j = 0; j < 4; j++) {
                int h = h_hi + j;
                if (h < H) z[base + h] = fmaf(acc[i][4 + j], inv_norm[h], b_enc[h]);
            }
        }
    }
}

// ---------------------------------------------------------------------------
// Kernel 3: out0 = x (straight-through forward value)
// ---------------------------------------------------------------------------
__global__ __launch_bounds__(256)
void copy_kernel(const float4* __restrict__ in, float4* __restrict__ out, int n4) {
    int i = blockIdx.x * blockDim.x + threadIdx.x;
    if (i < n4) out[i] = in[i];
}

// ---------------------------------------------------------------------------
// Kernel 4: per-row top-K mask (jax.lax.top_k tie semantics: lowest index
// wins among equal values). One block per row; MSB-first 8-bit radix select.
// ---------------------------------------------------------------------------
__global__ __launch_bounds__(256)
void topk_kernel(const float* __restrict__ z, float* __restrict__ zbar,
                 int H, int k) {
    const int row = blockIdx.x;
    const float* zr = z + (size_t)row * H;
    const int tid = threadIdx.x;
    __shared__ unsigned hist[256];
    __shared__ unsigned sh_pre;
    __shared__ int sh_k;
    __shared__ int sh_cnt;
    __shared__ int sh_cut;
    __shared__ int eq_idx[256];

    unsigned pre = 0;
    int kk = k;
    for (int round = 0; round < 4; ++round) {
        int shift = 24 - 8 * round;
        hist[tid] = 0;
        __syncthreads();
        for (int i = tid; i < H; i += 256) {
            unsigned key = fkey(zr[i]);
            bool match = (round == 0) || ((key >> (shift + 8)) == (pre >> (shift + 8)));
            if (match) atomicAdd(&hist[(key >> shift) & 0xFFu], 1u);
        }
        __syncthreads();
        if (tid == 0) {
            int acc = 0;
            int b = 255;
            for (; b > 0; --b) {
                int c = (int)hist[b];
                if (acc + c >= kk) break;
                acc += c;
            }
            sh_pre = pre | ((unsigned)b << shift);
            sh_k = kk - acc;
        }
        __syncthreads();
        pre = sh_pre;
        kk = sh_k;
        __syncthreads();
    }
    const unsigned kth = pre;  // exact key of the k-th largest element
    const int r = kk;          // how many elements equal to kth to keep

    if (tid == 0) sh_cnt = 0;
    __syncthreads();
    for (int i = tid; i < H; i += 256) {
        if (fkey(zr[i]) == kth) {
            int p = atomicAdd(&sh_cnt, 1);
            if (p < 256) eq_idx[p] = i;
        }
    }
    __syncthreads();
    int cnt = sh_cnt;

    if (cnt == r) {
        if (tid == 0) sh_cut = H;  // keep all equals
        __syncthreads();
    } else if (cnt <= 256) {
        if (tid == 0) {
            int cut = -1;
            for (int t = 0; t < r; t++) {
                int mn = 0x7FFFFFFF, mi = -1;
                for (int j = 0; j < cnt; j++) {
                    if (eq_idx[j] < mn) { mn = eq_idx[j]; mi = j; }
                }
                cut = mn;
                eq_idx[mi] = 0x7FFFFFFF;
            }
            sh_cut = cut;
        }
        __syncthreads();
    } else {
        // Pathological duplicate count: binary search smallest t with
        // #{i < t : key==kth} >= r; cut = t-1. Uniform branch per block.
        int lo = 0, hi = H;
        while (hi - lo > 1) {
            int mid = (lo + hi) >> 1;
            if (tid == 0) sh_cnt = 0;
            __syncthreads();
            int local = 0;
            for (int i = tid; i < mid; i += 256)
                if (fkey(zr[i]) == kth) local++;
            atomicAdd(&sh_cnt, local);
            __syncthreads();
            int c = sh_cnt;
            if (c >= r) hi = mid; else lo = mid;
            __syncthreads();
        }
        if (tid == 0) sh_cut = hi - 1;
        __syncthreads();
    }
    int cut = sh_cut;

    for (int i = tid; i < H; i += 256) {
        float v = zr[i];
        unsigned key = fkey(v);
        bool keep = (key > kth) || ((key == kth) && (i <= cut));
        zbar[(size_t)row * H + i] = keep ? v : 0.f;
    }
}

// ---------------------------------------------------------------------------
extern "C" void kernel_launch(void* const* d_in, const int* in_sizes, int n_in,
                              void* d_out, int out_size, void* d_ws, size_t ws_size,
                              hipStream_t stream) {
    const float* x     = (const float*)d_in[0];
    const float* v_enc = (const float*)d_in[1];
    const float* g_enc = (const float*)d_in[2];
    const float* b_enc = (const float*)d_in[3];
    // d_in[4] (v_dec) is dead in the forward value: x_recon == x.

    const int H = in_sizes[2];              // 30000
    const int D = in_sizes[1] / H;          // 768
    const int N = in_sizes[0] / D;          // 4096

    float* out0 = (float*)d_out;                    // x_recon == x   [N,D]
    float* z    = out0 + (size_t)N * D;             // z              [N,H]
    float* zbar = z + (size_t)N * H;                // z_bar          [N,H]

    float* inv_norm = (float*)d_ws;                 // [H]

    // 1) encoder weight_norm scale
    enc_norm_kernel<<<H, 256, 0, stream>>>(v_enc, g_enc, inv_norm, H, D);

    // 2) z = x @ w_enc.T + b_enc
    dim3 ggrid((H + BN - 1) / BN, N / BM);
    enc_gemm_kernel<<<ggrid, 256, 0, stream>>>(x, v_enc, inv_norm, b_enc, z, N, D, H);

    // 3) out0 = x
    int n4 = (N * D) / 4;
    copy_kernel<<<(n4 + 255) / 256, 256, 0, stream>>>((const float4*)x, (float4*)out0, n4);

    // 4) z_bar = top-K mask of z
    topk_kernel<<<N, 256, 0, stream>>>(z, zbar, H, TOPK);
}